// Round 13
// baseline (194.492 us; speedup 1.0000x reference)
//
#include <hip/hip_runtime.h>
#include <hip/hip_bf16.h>
#include <math.h>

typedef unsigned short u16;
typedef unsigned int u32;
typedef __bf16 bf16x8 __attribute__((ext_vector_type(8)));
typedef float f32x4 __attribute__((ext_vector_type(4)));

// B=8, T=128, S=512, E=D=512, fp32 in/out. d_out: h_tilde | wc | attn (fp32).
#define OUT_WC   524288LL
#define OUT_ATTN 1048576LL
#define C2 2.8853900817779268f   // 2*log2(e)
#define LOG2E 1.4426950408889634f
#define PLAS 72                  // proj LDS stride: 64 + 8 pad (u16)

// bf16 pool element offsets (in ws at +6MB)
#define P_ENC    0LL
#define P_HID    2097152LL
#define P_WATTN  2621440LL
#define P_WOUTR  3145728LL   // Wout[:,512:] compacted, [n][d] ld 512
#define P_WOUTTL 3407872LL   // Wout[:,:512] transposed, [d][n] ld 512

__device__ inline u16 f2b(float f) {
    return (u16)((__float_as_uint(f) + 0x8000u) >> 16);
}
__device__ inline float b2f(u16 v) { return __uint_as_float(((u32)v) << 16); }
__device__ inline u32 pkcvt(float x, float y) {
    __hip_bfloat162 h = __float22bfloat162_rn(make_float2(x, y));
    return *(u32*)&h;
}
__device__ inline float tanh_fast(float x) {
    return 1.f - 2.f * __builtin_amdgcn_rcpf(__builtin_amdgcn_exp2f(C2 * x) + 1.f);
}

// =============== tobf: bf16 pre-convert + Wout-left transpose ================
__global__ __launch_bounds__(256) void tobf(
    const float* __restrict__ enc, const float* __restrict__ hidden,
    const float* __restrict__ Wattn, const float* __restrict__ Wout,
    u16* __restrict__ dst)
{
    const int tid = threadIdx.x;
    if (blockIdx.x < 1664) {
        long long i = ((long long)blockIdx.x * 256 + tid) * 8;
        const float* src;
        if (i < 2097152)      src = enc + i;
        else if (i < 2621440) src = hidden + (i - 2097152);
        else if (i < 3145728) src = Wattn + (i - 2621440);
        else {
            long long j = i - 3145728;                      // WoutR: [n][d] ld512
            src = Wout + ((j >> 9) << 10) + 512 + (j & 511);
        }
        float4 v0 = *(const float4*)src;
        float4 v1 = *(const float4*)(src + 4);
        *(uint4*)(dst + i) = make_uint4(pkcvt(v0.x, v0.y), pkcvt(v0.z, v0.w),
                                        pkcvt(v1.x, v1.y), pkcvt(v1.z, v1.w));
    } else {
        __shared__ u32 lt[64 * 66];
        int tt = blockIdx.x - 1664;
        int n0 = (tt >> 3) * 64, d0 = (tt & 7) * 64;
        int r = tid >> 2, c = (tid & 3) * 16;
        const float* sp = Wout + (long long)(n0 + r) * 1024 + d0 + c;
        #pragma unroll
        for (int q = 0; q < 4; ++q) {
            float4 v = *(const float4*)(sp + q * 4);
            lt[r * 66 + c + q * 4 + 0] = f2b(v.x);
            lt[r * 66 + c + q * 4 + 1] = f2b(v.y);
            lt[r * 66 + c + q * 4 + 2] = f2b(v.z);
            lt[r * 66 + c + q * 4 + 3] = f2b(v.w);
        }
        __syncthreads();
        int dr = tid >> 2, nc = (tid & 3) * 16;
        u32 o[8];
        #pragma unroll
        for (int q = 0; q < 8; ++q) {
            u32 lo = lt[(nc + 2 * q) * 66 + dr];
            u32 hi = lt[(nc + 2 * q + 1) * 66 + dr];
            o[q] = lo | (hi << 16);
        }
        u16* dp = dst + P_WOUTTL + (long long)(d0 + dr) * 512 + n0 + nc;
        *(uint4*)dp       = make_uint4(o[0], o[1], o[2], o[3]);
        *(uint4*)(dp + 8) = make_uint4(o[4], o[5], o[6], o[7]);
    }
}

// =============== proj: 768 blocks, 64x64 tiles, BK=64, reg-prefetch ==========
// blocks 0..511:   ept[b][k][s] = exp2(C2 * We@enc^T)  (bf16 out)
// blocks 512..639: hp = C2*(hidden@Wh^T + battn)       (f32)
// blocks 640..767: hh = hidden@WoutR^T -> d_out[0..]   (f32)
__global__ __launch_bounds__(256) void proj(
    const u16* __restrict__ pool, const float* __restrict__ battn,
    float* __restrict__ hp, u16* __restrict__ ept, float* __restrict__ hh)
{
    __shared__ u16 lA[64 * PLAS];
    __shared__ u16 lB[64 * PLAS];
    const int tid = threadIdx.x;
    const int wvi = tid >> 6, ln = tid & 63;
    const int wm = wvi >> 1, wn = wvi & 1;
    const int l16 = ln & 15, quad = ln >> 4;
    const int blk = blockIdx.x;
    int bx, by, zz = 0, lda, ldb, mode;
    const u16 *A, *B;
    if (blk < 512) {
        mode = 0;
        zz = blk >> 6; by = (blk >> 3) & 7; bx = blk & 7;
        A = pool + P_WATTN + 512; lda = 1024;
        B = pool + P_ENC + (long long)zz * 262144; ldb = 512;
    } else if (blk < 640) {
        mode = 1;
        int i = blk - 512; by = i >> 3; bx = i & 7;
        A = pool + P_HID; lda = 512;
        B = pool + P_WATTN; ldb = 1024;
    } else {
        mode = 2;
        int i = blk - 640; by = i >> 3; bx = i & 7;
        A = pool + P_HID; lda = 512;
        B = pool + P_WOUTR; ldb = 512;
    }
    const int m0 = by * 64, n0 = bx * 64;
    const int sr = tid >> 2, sc = (tid & 3) * 16;
    const u16* Ap = A + (long long)(m0 + sr) * lda + sc;
    const u16* Bp = B + (long long)(n0 + sr) * ldb + sc;

    f32x4 acc[2][2] = {};
    uint4 ra0 = *(const uint4*)(Ap);
    uint4 ra1 = *(const uint4*)(Ap + 8);
    uint4 rb0 = *(const uint4*)(Bp);
    uint4 rb1 = *(const uint4*)(Bp + 8);

    for (int k0 = 0; k0 < 512; k0 += 64) {
        __syncthreads();
        *(uint4*)&lA[sr * PLAS + sc]     = ra0;
        *(uint4*)&lA[sr * PLAS + sc + 8] = ra1;
        *(uint4*)&lB[sr * PLAS + sc]     = rb0;
        *(uint4*)&lB[sr * PLAS + sc + 8] = rb1;
        __syncthreads();
        if (k0 < 448) {   // prefetch next BK-tile during MFMA burst
            ra0 = *(const uint4*)(Ap + k0 + 64);
            ra1 = *(const uint4*)(Ap + k0 + 72);
            rb0 = *(const uint4*)(Bp + k0 + 64);
            rb1 = *(const uint4*)(Bp + k0 + 72);
        }
        #pragma unroll
        for (int kk = 0; kk < 2; ++kk) {
            bf16x8 a0 = *(const bf16x8*)&lA[(wm * 32      + l16) * PLAS + kk * 32 + quad * 8];
            bf16x8 a1 = *(const bf16x8*)&lA[(wm * 32 + 16 + l16) * PLAS + kk * 32 + quad * 8];
            bf16x8 b0 = *(const bf16x8*)&lB[(wn * 32      + l16) * PLAS + kk * 32 + quad * 8];
            bf16x8 b1 = *(const bf16x8*)&lB[(wn * 32 + 16 + l16) * PLAS + kk * 32 + quad * 8];
            acc[0][0] = __builtin_amdgcn_mfma_f32_16x16x32_bf16(a0, b0, acc[0][0], 0, 0, 0);
            acc[0][1] = __builtin_amdgcn_mfma_f32_16x16x32_bf16(a0, b1, acc[0][1], 0, 0, 0);
            acc[1][0] = __builtin_amdgcn_mfma_f32_16x16x32_bf16(a1, b0, acc[1][0], 0, 0, 0);
            acc[1][1] = __builtin_amdgcn_mfma_f32_16x16x32_bf16(a1, b1, acc[1][1], 0, 0, 0);
        }
    }

    #pragma unroll
    for (int i = 0; i < 2; ++i) {
        #pragma unroll
        for (int j = 0; j < 2; ++j) {
            #pragma unroll
            for (int r = 0; r < 4; ++r) {
                int m = m0 + wm * 32 + i * 16 + quad * 4 + r;
                int n = n0 + wn * 32 + j * 16 + l16;
                float v = acc[i][j][r];
                if (mode == 0)
                    ept[(long long)zz * 262144 + (long long)m * 512 + n] =
                        f2b(__builtin_amdgcn_exp2f(C2 * v));
                else if (mode == 1)
                    hp[(long long)m * 512 + n] = C2 * (v + battn[n]);
                else
                    hh[(long long)m * 512 + n] = v;
            }
        }
    }
}

// =============== reductions (16-wave, 1024 threads) ==========================
__device__ inline float wred_sum(float v) {
    #pragma unroll
    for (int i = 32; i > 0; i >>= 1) v += __shfl_xor(v, i);
    return v;
}
__device__ inline float wred_max(float v) {
    #pragma unroll
    for (int i = 32; i > 0; i >>= 1) v = fmaxf(v, __shfl_xor(v, i));
    return v;
}
__device__ inline float bred_sum16(float v, float* red, int tid) {
    v = wred_sum(v);
    __syncthreads();
    if ((tid & 63) == 0) red[tid >> 6] = v;
    __syncthreads();
    float s = 0.f;
    #pragma unroll
    for (int i = 0; i < 16; ++i) s += red[i];
    return s;
}
// row-wise over half-blocks: waves 0..7 = row 0, waves 8..15 = row 1
__device__ inline float bred_rowmax(float v, float* red, int tid) {
    v = wred_max(v);
    __syncthreads();
    if ((tid & 63) == 0) red[tid >> 6] = v;
    __syncthreads();
    int base = (tid >> 9) * 8;
    float m = red[base];
    #pragma unroll
    for (int i = 1; i < 8; ++i) m = fmaxf(m, red[base + i]);
    return m;
}
__device__ inline float bred_rowsum(float v, float* red, int tid) {
    v = wred_sum(v);
    __syncthreads();
    if ((tid & 63) == 0) red[tid >> 6] = v;
    __syncthreads();
    int base = (tid >> 9) * 8;
    float s = 0.f;
    #pragma unroll
    for (int i = 0; i < 8; ++i) s += red[base + i];
    return s;
}

// =============== energies + softmax + wc + h_tilde (1024 threads) ============
__device__ inline void proc8(uint4 c, float4 hw, float* a0, float* a1) {
    u32 cc[4] = {c.x, c.y, c.z, c.w};
    #pragma unroll
    for (int i = 0; i < 4; ++i) {
        float xl = __uint_as_float(cc[i] << 16);
        float xh = __uint_as_float(cc[i] & 0xFFFF0000u);
        float rl0 = __builtin_amdgcn_rcpf(fmaf(hw.x, xl, 1.f));
        float rh0 = __builtin_amdgcn_rcpf(fmaf(hw.x, xh, 1.f));
        float rl1 = __builtin_amdgcn_rcpf(fmaf(hw.y, xl, 1.f));
        float rh1 = __builtin_amdgcn_rcpf(fmaf(hw.y, xh, 1.f));
        a0[2*i]   = fmaf(hw.z, rl0, a0[2*i]);
        a0[2*i+1] = fmaf(hw.z, rh0, a0[2*i+1]);
        a1[2*i]   = fmaf(hw.z, rl1, a1[2*i]);
        a1[2*i+1] = fmaf(hw.z, rh1, a1[2*i+1]);
    }
}

__global__ __launch_bounds__(1024, 8) void energies(
    const float* __restrict__ maskp, const float* __restrict__ hp,
    const u16* __restrict__ ept, const float* __restrict__ Wv,
    const float* __restrict__ bvp, const u16* __restrict__ pool,
    float* __restrict__ out)
{
    __shared__ __align__(16) float4 hpw[512];   //  8KB; aliased as aL|wcL later
    __shared__ float pa[2][16][512];            // 64KB; reused as combine scratch
    __shared__ float red[16];
    float* aLf = (float*)hpw;                   // aL: float[1024] = (at0,at1) per s
    float2* wcL = ((float2*)hpw) + 512;         // wc rows, 4KB (second half of hpw)
    const int tid = threadIdx.x;
    const int b = blockIdx.x >> 6;
    const int t0 = (blockIdx.x & 63) * 2;
    const u16* enc_bf = pool + P_ENC;
    const u16* woutT  = pool + P_WOUTTL;

    float w = 0.f;
    if (tid < 512) {
        w = Wv[tid];
        float h0 = hp[(long long)(b * 128 + t0) * 512 + tid];
        float h1 = hp[(long long)(b * 128 + t0 + 1) * 512 + tid];
        hpw[tid] = make_float4(__builtin_amdgcn_exp2f(h0), __builtin_amdgcn_exp2f(h1), w, 0.f);
    }
    float sumWv = bred_sum16(w, red, tid);   // barriers also publish hpw

    // main loop: 16 k-groups x 32 k; thread owns 8 s x 2 t
    const int kg = tid >> 6, sl = tid & 63;
    const int s0 = sl * 8;
    const u16* eb = ept + (long long)b * 262144 + (kg * 32) * 512 + s0;
    const float4* hq = &hpw[kg * 32];

    float a0[8] = {0,0,0,0,0,0,0,0}, a1[8] = {0,0,0,0,0,0,0,0};
    uint4 c0 = *(const uint4*)(eb);
    uint4 c1 = *(const uint4*)(eb + 512);
    uint4 c2 = *(const uint4*)(eb + 1024);
    uint4 c3 = *(const uint4*)(eb + 1536);
    for (int kk = 0; kk < 28; kk += 4) {
        const u16* nb = eb + (kk + 4) * 512;
        uint4 n0 = *(const uint4*)(nb);
        uint4 n1 = *(const uint4*)(nb + 512);
        uint4 n2 = *(const uint4*)(nb + 1024);
        uint4 n3 = *(const uint4*)(nb + 1536);
        proc8(c0, hq[kk],     a0, a1);
        proc8(c1, hq[kk + 1], a0, a1);
        proc8(c2, hq[kk + 2], a0, a1);
        proc8(c3, hq[kk + 3], a0, a1);
        c0 = n0; c1 = n1; c2 = n2; c3 = n3;
    }
    proc8(c0, hq[28], a0, a1);
    proc8(c1, hq[29], a0, a1);
    proc8(c2, hq[30], a0, a1);
    proc8(c3, hq[31], a0, a1);

    *(float4*)&pa[0][kg][s0]     = make_float4(a0[0], a0[1], a0[2], a0[3]);
    *(float4*)&pa[0][kg][s0 + 4] = make_float4(a0[4], a0[5], a0[6], a0[7]);
    *(float4*)&pa[1][kg][s0]     = make_float4(a1[0], a1[1], a1[2], a1[3]);
    *(float4*)&pa[1][kg][s0 + 4] = make_float4(a1[4], a1[5], a1[6], a1[7]);
    __syncthreads();

    // combine + softmax: thread owns (row rr, s); rows are wave-aligned halves
    const int rr = tid >> 9, s = tid & 511;
    float A = 0.f;
    #pragma unroll
    for (int g = 0; g < 16; ++g) A += pa[rr][g][s];
    float mv = maskp[(long long)b * 512 + s];
    float r = (bvp[0] + sumWv - 2.f * A) * mv; r *= mv;
    float mx = bred_rowmax(r, red, tid);
    float ex = __builtin_amdgcn_exp2f((r - mx) * LOG2E) * mv;
    float sm = bred_rowsum(ex, red, tid);
    float at = ex * (1.f / (sm + 1e-6f));
    out[OUT_ATTN + (long long)(b * 128 + t0 + rr) * 512 + s] = at;
    aLf[s * 2 + rr] = at;                        // hpw is dead; alias as aL
    __syncthreads();

    const float* wp = (const float*)pa;          // combine scratch (pa is dead)
    float* wpw = (float*)pa;
    const int half = tid >> 9, e = tid & 511;

    // wc phase: thread owns e; s-half per thread-half; group-ahead prefetch
    {
        const u16* encb = enc_bf + (long long)b * 262144 + (long long)(half * 256) * 512 + e;
        const float4* aL4 = (const float4*)aLf + half * 128;   // s-pairs of this half
        float acc0 = 0.f, acc1 = 0.f;
        float ev[8];
        #pragma unroll
        for (int i = 0; i < 8; ++i) ev[i] = b2f(encb[i * 512]);
        for (int ss = 0; ss < 248; ss += 8) {
            float nv[8];
            #pragma unroll
            for (int i = 0; i < 8; ++i) nv[i] = b2f(encb[(ss + 8 + i) * 512]);
            #pragma unroll
            for (int i = 0; i < 4; ++i) {
                float4 ap = aL4[(ss >> 1) + i];
                acc0 = fmaf(ap.x, ev[2*i],   acc0);
                acc1 = fmaf(ap.y, ev[2*i],   acc1);
                acc0 = fmaf(ap.z, ev[2*i+1], acc0);
                acc1 = fmaf(ap.w, ev[2*i+1], acc1);
            }
            #pragma unroll
            for (int i = 0; i < 8; ++i) ev[i] = nv[i];
        }
        #pragma unroll
        for (int i = 0; i < 4; ++i) {
            float4 ap = aL4[124 + i];
            acc0 = fmaf(ap.x, ev[2*i],   acc0);
            acc1 = fmaf(ap.y, ev[2*i],   acc1);
            acc0 = fmaf(ap.z, ev[2*i+1], acc0);
            acc1 = fmaf(ap.w, ev[2*i+1], acc1);
        }
        if (half) { wpw[e] = acc0; wpw[512 + e] = acc1; }
        __syncthreads();
        if (!half) {
            acc0 += wp[e]; acc1 += wp[512 + e];
            out[OUT_WC + (long long)(b * 128 + t0) * 512 + e]     = acc0;
            out[OUT_WC + (long long)(b * 128 + t0 + 1) * 512 + e] = acc1;
            wcL[e] = make_float2(acc0, acc1);
        }
        __syncthreads();
    }

    // h_tilde phase: thread owns n; d-half per thread-half
    {
        const int n = e;
        const u16* wt = woutT + (long long)(half * 256) * 512 + n;
        const float4* wL4 = (const float4*)wcL + half * 128;   // FIX R12: 256 d = 128 float4
        float acc0 = 0.f, acc1 = 0.f;
        float wv[8];
        #pragma unroll
        for (int i = 0; i < 8; ++i) wv[i] = b2f(wt[i * 512]);
        for (int dd = 0; dd < 248; dd += 8) {
            float nv[8];
            #pragma unroll
            for (int i = 0; i < 8; ++i) nv[i] = b2f(wt[(dd + 8 + i) * 512]);
            #pragma unroll
            for (int i = 0; i < 4; ++i) {
                float4 cp = wL4[(dd >> 1) + i];
                acc0 = fmaf(cp.x, wv[2*i],   acc0);
                acc1 = fmaf(cp.y, wv[2*i],   acc1);
                acc0 = fmaf(cp.z, wv[2*i+1], acc0);
                acc1 = fmaf(cp.w, wv[2*i+1], acc1);
            }
            #pragma unroll
            for (int i = 0; i < 8; ++i) wv[i] = nv[i];
        }
        #pragma unroll
        for (int i = 0; i < 4; ++i) {
            float4 cp = wL4[124 + i];
            acc0 = fmaf(cp.x, wv[2*i],   acc0);
            acc1 = fmaf(cp.y, wv[2*i],   acc1);
            acc0 = fmaf(cp.z, wv[2*i+1], acc0);
            acc1 = fmaf(cp.w, wv[2*i+1], acc1);
        }
        __syncthreads();
        if (half) { wpw[n] = acc0; wpw[512 + n] = acc1; }
        __syncthreads();
        if (!half) {
            acc0 += wp[n]; acc1 += wp[512 + n];
            long long o0 = (long long)(b * 128 + t0) * 512 + n;
            long long o1 = (long long)(b * 128 + t0 + 1) * 512 + n;
            out[o0] = tanh_fast(acc0 + out[o0]);   // out holds hh from proj
            out[o1] = tanh_fast(acc1 + out[o1]);
        }
    }
}

extern "C" void kernel_launch(void* const* d_in, const int* in_sizes, int n_in,
                              void* d_out, int out_size, void* d_ws, size_t ws_size,
                              hipStream_t stream)
{
    const float* hidden = (const float*)d_in[0];
    const float* enc    = (const float*)d_in[1];
    const float* mask   = (const float*)d_in[2];
    const float* Wattn  = (const float*)d_in[3];
    const float* battn  = (const float*)d_in[4];
    const float* Wv     = (const float*)d_in[5];
    const float* bvp    = (const float*)d_in[6];
    const float* Wout   = (const float*)d_in[7];
    float* out = (float*)d_out;

    float* hp  = (float*)d_ws;                      // @0   2MB fp32
    u16*   ept = (u16*)((char*)d_ws + (2 << 20));   // @2M  4MB bf16 (exp2 domain)
    u16*   pool = (u16*)((char*)d_ws + (6 << 20));  // @6M  ~7.3MB bf16 pool

    tobf<<<1728, 256, 0, stream>>>(enc, hidden, Wattn, Wout, pool);
    proj<<<768, 256, 0, stream>>>(pool, battn, hp, ept, out /* hh in-place */);
    energies<<<512, 1024, 0, stream>>>(mask, hp, ept, Wv, bvp, pool, out);
}

// Round 14
// 167.216 us; speedup vs baseline: 1.1631x; 1.1631x over previous
//
#include <hip/hip_runtime.h>
#include <hip/hip_bf16.h>
#include <math.h>

typedef unsigned short u16;
typedef unsigned int u32;
typedef __bf16 bf16x8 __attribute__((ext_vector_type(8)));
typedef float f32x4 __attribute__((ext_vector_type(4)));

// B=8, T=128, S=512, E=D=512, fp32 in/out. d_out: h_tilde | wc | attn (fp32).
#define OUT_WC   524288LL
#define OUT_ATTN 1048576LL
#define C2 2.8853900817779268f   // 2*log2(e)
#define LOG2E 1.4426950408889634f
#define PLAS 72                  // proj LDS stride: 64 + 8 pad (u16)

// bf16 pool element offsets (in ws at +6MB)
#define P_ENC    0LL
#define P_HID    2097152LL
#define P_WATTN  2621440LL
#define P_WOUTR  3145728LL   // Wout[:,512:] compacted, [n][d] ld 512
#define P_WOUTTL 3407872LL   // Wout[:,:512] transposed, [d][n] ld 512

__device__ inline u16 f2b(float f) {
    return (u16)((__float_as_uint(f) + 0x8000u) >> 16);
}
__device__ inline float b2f(u16 v) { return __uint_as_float(((u32)v) << 16); }
__device__ inline u32 pkcvt(float x, float y) {
    __hip_bfloat162 h = __float22bfloat162_rn(make_float2(x, y));
    return *(u32*)&h;
}
__device__ inline float tanh_fast(float x) {
    return 1.f - 2.f * __builtin_amdgcn_rcpf(__builtin_amdgcn_exp2f(C2 * x) + 1.f);
}

// =============== tobf: bf16 pre-convert + Wout-left transpose ================
__global__ __launch_bounds__(256) void tobf(
    const float* __restrict__ enc, const float* __restrict__ hidden,
    const float* __restrict__ Wattn, const float* __restrict__ Wout,
    u16* __restrict__ dst)
{
    const int tid = threadIdx.x;
    if (blockIdx.x < 1664) {
        long long i = ((long long)blockIdx.x * 256 + tid) * 8;
        const float* src;
        if (i < 2097152)      src = enc + i;
        else if (i < 2621440) src = hidden + (i - 2097152);
        else if (i < 3145728) src = Wattn + (i - 2621440);
        else {
            long long j = i - 3145728;                      // WoutR: [n][d] ld512
            src = Wout + ((j >> 9) << 10) + 512 + (j & 511);
        }
        float4 v0 = *(const float4*)src;
        float4 v1 = *(const float4*)(src + 4);
        *(uint4*)(dst + i) = make_uint4(pkcvt(v0.x, v0.y), pkcvt(v0.z, v0.w),
                                        pkcvt(v1.x, v1.y), pkcvt(v1.z, v1.w));
    } else {
        __shared__ u32 lt[64 * 66];
        int tt = blockIdx.x - 1664;
        int n0 = (tt >> 3) * 64, d0 = (tt & 7) * 64;
        int r = tid >> 2, c = (tid & 3) * 16;
        const float* sp = Wout + (long long)(n0 + r) * 1024 + d0 + c;
        #pragma unroll
        for (int q = 0; q < 4; ++q) {
            float4 v = *(const float4*)(sp + q * 4);
            lt[r * 66 + c + q * 4 + 0] = f2b(v.x);
            lt[r * 66 + c + q * 4 + 1] = f2b(v.y);
            lt[r * 66 + c + q * 4 + 2] = f2b(v.z);
            lt[r * 66 + c + q * 4 + 3] = f2b(v.w);
        }
        __syncthreads();
        int dr = tid >> 2, nc = (tid & 3) * 16;
        u32 o[8];
        #pragma unroll
        for (int q = 0; q < 8; ++q) {
            u32 lo = lt[(nc + 2 * q) * 66 + dr];
            u32 hi = lt[(nc + 2 * q + 1) * 66 + dr];
            o[q] = lo | (hi << 16);
        }
        u16* dp = dst + P_WOUTTL + (long long)(d0 + dr) * 512 + n0 + nc;
        *(uint4*)dp       = make_uint4(o[0], o[1], o[2], o[3]);
        *(uint4*)(dp + 8) = make_uint4(o[4], o[5], o[6], o[7]);
    }
}

// =============== proj: 768 blocks, 64x64 tiles, BK=64, reg-prefetch ==========
__global__ __launch_bounds__(256) void proj(
    const u16* __restrict__ pool, const float* __restrict__ battn,
    float* __restrict__ hp, u16* __restrict__ ept, float* __restrict__ hh)
{
    __shared__ u16 lA[64 * PLAS];
    __shared__ u16 lB[64 * PLAS];
    const int tid = threadIdx.x;
    const int wvi = tid >> 6, ln = tid & 63;
    const int wm = wvi >> 1, wn = wvi & 1;
    const int l16 = ln & 15, quad = ln >> 4;
    const int blk = blockIdx.x;
    int bx, by, zz = 0, lda, ldb, mode;
    const u16 *A, *B;
    if (blk < 512) {
        mode = 0;
        zz = blk >> 6; by = (blk >> 3) & 7; bx = blk & 7;
        A = pool + P_WATTN + 512; lda = 1024;
        B = pool + P_ENC + (long long)zz * 262144; ldb = 512;
    } else if (blk < 640) {
        mode = 1;
        int i = blk - 512; by = i >> 3; bx = i & 7;
        A = pool + P_HID; lda = 512;
        B = pool + P_WATTN; ldb = 1024;
    } else {
        mode = 2;
        int i = blk - 640; by = i >> 3; bx = i & 7;
        A = pool + P_HID; lda = 512;
        B = pool + P_WOUTR; ldb = 512;
    }
    const int m0 = by * 64, n0 = bx * 64;
    const int sr = tid >> 2, sc = (tid & 3) * 16;
    const u16* Ap = A + (long long)(m0 + sr) * lda + sc;
    const u16* Bp = B + (long long)(n0 + sr) * ldb + sc;

    f32x4 acc[2][2] = {};
    uint4 ra0 = *(const uint4*)(Ap);
    uint4 ra1 = *(const uint4*)(Ap + 8);
    uint4 rb0 = *(const uint4*)(Bp);
    uint4 rb1 = *(const uint4*)(Bp + 8);

    for (int k0 = 0; k0 < 512; k0 += 64) {
        __syncthreads();
        *(uint4*)&lA[sr * PLAS + sc]     = ra0;
        *(uint4*)&lA[sr * PLAS + sc + 8] = ra1;
        *(uint4*)&lB[sr * PLAS + sc]     = rb0;
        *(uint4*)&lB[sr * PLAS + sc + 8] = rb1;
        __syncthreads();
        if (k0 < 448) {   // prefetch next BK-tile during MFMA burst
            ra0 = *(const uint4*)(Ap + k0 + 64);
            ra1 = *(const uint4*)(Ap + k0 + 72);
            rb0 = *(const uint4*)(Bp + k0 + 64);
            rb1 = *(const uint4*)(Bp + k0 + 72);
        }
        #pragma unroll
        for (int kk = 0; kk < 2; ++kk) {
            bf16x8 a0 = *(const bf16x8*)&lA[(wm * 32      + l16) * PLAS + kk * 32 + quad * 8];
            bf16x8 a1 = *(const bf16x8*)&lA[(wm * 32 + 16 + l16) * PLAS + kk * 32 + quad * 8];
            bf16x8 b0 = *(const bf16x8*)&lB[(wn * 32      + l16) * PLAS + kk * 32 + quad * 8];
            bf16x8 b1 = *(const bf16x8*)&lB[(wn * 32 + 16 + l16) * PLAS + kk * 32 + quad * 8];
            acc[0][0] = __builtin_amdgcn_mfma_f32_16x16x32_bf16(a0, b0, acc[0][0], 0, 0, 0);
            acc[0][1] = __builtin_amdgcn_mfma_f32_16x16x32_bf16(a0, b1, acc[0][1], 0, 0, 0);
            acc[1][0] = __builtin_amdgcn_mfma_f32_16x16x32_bf16(a1, b0, acc[1][0], 0, 0, 0);
            acc[1][1] = __builtin_amdgcn_mfma_f32_16x16x32_bf16(a1, b1, acc[1][1], 0, 0, 0);
        }
    }

    #pragma unroll
    for (int i = 0; i < 2; ++i) {
        #pragma unroll
        for (int j = 0; j < 2; ++j) {
            #pragma unroll
            for (int r = 0; r < 4; ++r) {
                int m = m0 + wm * 32 + i * 16 + quad * 4 + r;
                int n = n0 + wn * 32 + j * 16 + l16;
                float v = acc[i][j][r];
                if (mode == 0)
                    ept[(long long)zz * 262144 + (long long)m * 512 + n] =
                        f2b(__builtin_amdgcn_exp2f(C2 * v));
                else if (mode == 1)
                    hp[(long long)m * 512 + n] = C2 * (v + battn[n]);
                else
                    hh[(long long)m * 512 + n] = v;
            }
        }
    }
}

// =============== reductions (16-wave, 1024 threads) ==========================
__device__ inline float wred_sum(float v) {
    #pragma unroll
    for (int i = 32; i > 0; i >>= 1) v += __shfl_xor(v, i);
    return v;
}
__device__ inline float wred_max(float v) {
    #pragma unroll
    for (int i = 32; i > 0; i >>= 1) v = fmaxf(v, __shfl_xor(v, i));
    return v;
}
__device__ inline float bred_sum16(float v, float* red, int tid) {
    v = wred_sum(v);
    __syncthreads();
    if ((tid & 63) == 0) red[tid >> 6] = v;
    __syncthreads();
    float s = 0.f;
    #pragma unroll
    for (int i = 0; i < 16; ++i) s += red[i];
    return s;
}
// row-wise over half-blocks: waves 0..7 = row 0, waves 8..15 = row 1
__device__ inline float bred_rowmax(float v, float* red, int tid) {
    v = wred_max(v);
    __syncthreads();
    if ((tid & 63) == 0) red[tid >> 6] = v;
    __syncthreads();
    int base = (tid >> 9) * 8;
    float m = red[base];
    #pragma unroll
    for (int i = 1; i < 8; ++i) m = fmaxf(m, red[base + i]);
    return m;
}
__device__ inline float bred_rowsum(float v, float* red, int tid) {
    v = wred_sum(v);
    __syncthreads();
    if ((tid & 63) == 0) red[tid >> 6] = v;
    __syncthreads();
    int base = (tid >> 9) * 8;
    float s = 0.f;
    #pragma unroll
    for (int i = 0; i < 8; ++i) s += red[base + i];
    return s;
}

// =============== energies + softmax + wc + h_tilde (1024 threads) ============
__device__ inline void proc8(uint4 c, float4 hw, float* a0, float* a1) {
    u32 cc[4] = {c.x, c.y, c.z, c.w};
    #pragma unroll
    for (int i = 0; i < 4; ++i) {
        float xl = __uint_as_float(cc[i] << 16);
        float xh = __uint_as_float(cc[i] & 0xFFFF0000u);
        float rl0 = __builtin_amdgcn_rcpf(fmaf(hw.x, xl, 1.f));
        float rh0 = __builtin_amdgcn_rcpf(fmaf(hw.x, xh, 1.f));
        float rl1 = __builtin_amdgcn_rcpf(fmaf(hw.y, xl, 1.f));
        float rh1 = __builtin_amdgcn_rcpf(fmaf(hw.y, xh, 1.f));
        a0[2*i]   = fmaf(hw.z, rl0, a0[2*i]);
        a0[2*i+1] = fmaf(hw.z, rh0, a0[2*i+1]);
        a1[2*i]   = fmaf(hw.z, rl1, a1[2*i]);
        a1[2*i+1] = fmaf(hw.z, rh1, a1[2*i+1]);
    }
}

// R13 ERRATUM: __launch_bounds__(1024, 8) strangled the allocator to 32 VGPRs
// -> 218 MB scratch spill. (1024, 4) caps at 128; compiler lands ~60 which
// still allows 2 blocks/CU (VGPR<=64, LDS 74.2KB x2 <= 160KB).
__global__ __launch_bounds__(1024, 4) void energies(
    const float* __restrict__ maskp, const float* __restrict__ hp,
    const u16* __restrict__ ept, const float* __restrict__ Wv,
    const float* __restrict__ bvp, const u16* __restrict__ pool,
    float* __restrict__ out)
{
    __shared__ __align__(16) float4 hpw[512];   //  8KB; aliased as aL|wcL later
    __shared__ float pa[2][16][512];            // 64KB; reused as combine scratch
    __shared__ float red[16];
    float* aLf = (float*)hpw;                   // aL: float[1024] = (at0,at1) per s
    float2* wcL = ((float2*)hpw) + 512;         // wc rows, 4KB (second half of hpw)
    const int tid = threadIdx.x;
    const int b = blockIdx.x >> 6;
    const int t0 = (blockIdx.x & 63) * 2;
    const u16* enc_bf = pool + P_ENC;
    const u16* woutT  = pool + P_WOUTTL;

    float w = 0.f;
    if (tid < 512) {
        w = Wv[tid];
        float h0 = hp[(long long)(b * 128 + t0) * 512 + tid];
        float h1 = hp[(long long)(b * 128 + t0 + 1) * 512 + tid];
        hpw[tid] = make_float4(__builtin_amdgcn_exp2f(h0), __builtin_amdgcn_exp2f(h1), w, 0.f);
    }
    float sumWv = bred_sum16(w, red, tid);   // barriers also publish hpw

    // main loop: 16 k-groups x 32 k; thread owns 8 s x 2 t
    const int kg = tid >> 6, sl = tid & 63;
    const int s0 = sl * 8;
    const u16* eb = ept + (long long)b * 262144 + (kg * 32) * 512 + s0;
    const float4* hq = &hpw[kg * 32];

    float a0[8] = {0,0,0,0,0,0,0,0}, a1[8] = {0,0,0,0,0,0,0,0};
    uint4 c0 = *(const uint4*)(eb);
    uint4 c1 = *(const uint4*)(eb + 512);
    uint4 c2 = *(const uint4*)(eb + 1024);
    uint4 c3 = *(const uint4*)(eb + 1536);
    for (int kk = 0; kk < 28; kk += 4) {
        const u16* nb = eb + (kk + 4) * 512;
        uint4 n0 = *(const uint4*)(nb);
        uint4 n1 = *(const uint4*)(nb + 512);
        uint4 n2 = *(const uint4*)(nb + 1024);
        uint4 n3 = *(const uint4*)(nb + 1536);
        proc8(c0, hq[kk],     a0, a1);
        proc8(c1, hq[kk + 1], a0, a1);
        proc8(c2, hq[kk + 2], a0, a1);
        proc8(c3, hq[kk + 3], a0, a1);
        c0 = n0; c1 = n1; c2 = n2; c3 = n3;
    }
    proc8(c0, hq[28], a0, a1);
    proc8(c1, hq[29], a0, a1);
    proc8(c2, hq[30], a0, a1);
    proc8(c3, hq[31], a0, a1);

    *(float4*)&pa[0][kg][s0]     = make_float4(a0[0], a0[1], a0[2], a0[3]);
    *(float4*)&pa[0][kg][s0 + 4] = make_float4(a0[4], a0[5], a0[6], a0[7]);
    *(float4*)&pa[1][kg][s0]     = make_float4(a1[0], a1[1], a1[2], a1[3]);
    *(float4*)&pa[1][kg][s0 + 4] = make_float4(a1[4], a1[5], a1[6], a1[7]);
    __syncthreads();

    // combine + softmax: thread owns (row rr, s); rows are wave-aligned halves
    const int rr = tid >> 9, s = tid & 511;
    float A = 0.f;
    #pragma unroll
    for (int g = 0; g < 16; ++g) A += pa[rr][g][s];
    float mv = maskp[(long long)b * 512 + s];
    float r = (bvp[0] + sumWv - 2.f * A) * mv; r *= mv;
    float mx = bred_rowmax(r, red, tid);
    float ex = __builtin_amdgcn_exp2f((r - mx) * LOG2E) * mv;
    float sm = bred_rowsum(ex, red, tid);
    float at = ex * (1.f / (sm + 1e-6f));
    out[OUT_ATTN + (long long)(b * 128 + t0 + rr) * 512 + s] = at;
    aLf[s * 2 + rr] = at;                        // hpw is dead; alias as aL
    __syncthreads();

    const float* wp = (const float*)pa;          // combine scratch (pa is dead)
    float* wpw = (float*)pa;
    const int half = tid >> 9, e = tid & 511;

    // wc phase: thread owns e; s-half per thread-half; group-ahead prefetch
    {
        const u16* encb = enc_bf + (long long)b * 262144 + (long long)(half * 256) * 512 + e;
        const float4* aL4 = (const float4*)aLf + half * 128;   // s-pairs of this half
        float acc0 = 0.f, acc1 = 0.f;
        float ev[8];
        #pragma unroll
        for (int i = 0; i < 8; ++i) ev[i] = b2f(encb[i * 512]);
        for (int ss = 0; ss < 248; ss += 8) {
            float nv[8];
            #pragma unroll
            for (int i = 0; i < 8; ++i) nv[i] = b2f(encb[(ss + 8 + i) * 512]);
            #pragma unroll
            for (int i = 0; i < 4; ++i) {
                float4 ap = aL4[(ss >> 1) + i];
                acc0 = fmaf(ap.x, ev[2*i],   acc0);
                acc1 = fmaf(ap.y, ev[2*i],   acc1);
                acc0 = fmaf(ap.z, ev[2*i+1], acc0);
                acc1 = fmaf(ap.w, ev[2*i+1], acc1);
            }
            #pragma unroll
            for (int i = 0; i < 8; ++i) ev[i] = nv[i];
        }
        #pragma unroll
        for (int i = 0; i < 4; ++i) {
            float4 ap = aL4[124 + i];
            acc0 = fmaf(ap.x, ev[2*i],   acc0);
            acc1 = fmaf(ap.y, ev[2*i],   acc1);
            acc0 = fmaf(ap.z, ev[2*i+1], acc0);
            acc1 = fmaf(ap.w, ev[2*i+1], acc1);
        }
        if (half) { wpw[e] = acc0; wpw[512 + e] = acc1; }
        __syncthreads();
        if (!half) {
            acc0 += wp[e]; acc1 += wp[512 + e];
            out[OUT_WC + (long long)(b * 128 + t0) * 512 + e]     = acc0;
            out[OUT_WC + (long long)(b * 128 + t0 + 1) * 512 + e] = acc1;
            wcL[e] = make_float2(acc0, acc1);
        }
        __syncthreads();
    }

    // h_tilde phase: thread owns n; d-half per thread-half
    {
        const int n = e;
        const u16* wt = woutT + (long long)(half * 256) * 512 + n;
        const float4* wL4 = (const float4*)wcL + half * 128;   // 256 d = 128 float4
        float acc0 = 0.f, acc1 = 0.f;
        float wv[8];
        #pragma unroll
        for (int i = 0; i < 8; ++i) wv[i] = b2f(wt[i * 512]);
        for (int dd = 0; dd < 248; dd += 8) {
            float nv[8];
            #pragma unroll
            for (int i = 0; i < 8; ++i) nv[i] = b2f(wt[(dd + 8 + i) * 512]);
            #pragma unroll
            for (int i = 0; i < 4; ++i) {
                float4 cp = wL4[(dd >> 1) + i];
                acc0 = fmaf(cp.x, wv[2*i],   acc0);
                acc1 = fmaf(cp.y, wv[2*i],   acc1);
                acc0 = fmaf(cp.z, wv[2*i+1], acc0);
                acc1 = fmaf(cp.w, wv[2*i+1], acc1);
            }
            #pragma unroll
            for (int i = 0; i < 8; ++i) wv[i] = nv[i];
        }
        #pragma unroll
        for (int i = 0; i < 4; ++i) {
            float4 cp = wL4[124 + i];
            acc0 = fmaf(cp.x, wv[2*i],   acc0);
            acc1 = fmaf(cp.y, wv[2*i],   acc1);
            acc0 = fmaf(cp.z, wv[2*i+1], acc0);
            acc1 = fmaf(cp.w, wv[2*i+1], acc1);
        }
        __syncthreads();
        if (half) { wpw[n] = acc0; wpw[512 + n] = acc1; }
        __syncthreads();
        if (!half) {
            acc0 += wp[n]; acc1 += wp[512 + n];
            long long o0 = (long long)(b * 128 + t0) * 512 + n;
            long long o1 = (long long)(b * 128 + t0 + 1) * 512 + n;
            out[o0] = tanh_fast(acc0 + out[o0]);   // out holds hh from proj
            out[o1] = tanh_fast(acc1 + out[o1]);
        }
    }
}

extern "C" void kernel_launch(void* const* d_in, const int* in_sizes, int n_in,
                              void* d_out, int out_size, void* d_ws, size_t ws_size,
                              hipStream_t stream)
{
    const float* hidden = (const float*)d_in[0];
    const float* enc    = (const float*)d_in[1];
    const float* mask   = (const float*)d_in[2];
    const float* Wattn  = (const float*)d_in[3];
    const float* battn  = (const float*)d_in[4];
    const float* Wv     = (const float*)d_in[5];
    const float* bvp    = (const float*)d_in[6];
    const float* Wout   = (const float*)d_in[7];
    float* out = (float*)d_out;

    float* hp  = (float*)d_ws;                      // @0   2MB fp32
    u16*   ept = (u16*)((char*)d_ws + (2 << 20));   // @2M  4MB bf16 (exp2 domain)
    u16*   pool = (u16*)((char*)d_ws + (6 << 20));  // @6M  ~7.3MB bf16 pool

    tobf<<<1728, 256, 0, stream>>>(enc, hidden, Wattn, Wout, pool);
    proj<<<768, 256, 0, stream>>>(pool, battn, hp, ept, out /* hh in-place */);
    energies<<<512, 1024, 0, stream>>>(mask, hp, ept, Wv, bvp, pool, out);
}